// Round 10
// baseline (162.054 us; speedup 1.0000x reference)
//
#include <hip/hip_runtime.h>
#include <hip/hip_bf16.h>

typedef __attribute__((ext_vector_type(4))) float f32x4;
typedef __attribute__((ext_vector_type(16))) float f32x16;
typedef __attribute__((ext_vector_type(8))) short bf8;
typedef __attribute__((ext_vector_type(2))) int i32x2;

#define B_ 2
#define ST 2048
#define SC 1024
#define SK 3072
#define NH 16
#define DH 128
#define KVB 32
#define NT 96
#define NP 48            // tile pairs (2 tiles per barrier)
#define TGTP 32          // pairs >= 32 are condition tiles
#define SCALE 0.088388347648318447f
#define LOG2E 1.4426950408889634f

__device__ __forceinline__ unsigned short f2bf(float f) {
    union { __hip_bfloat16 b; unsigned short u; } c;
    c.b = __float2bfloat16(f);
    return c.u;
}

__device__ __forceinline__ i32x2 tr_read(unsigned a) {
    i32x2 d;
    asm volatile("ds_read_b64_tr_b16 %0, %1" : "=v"(d) : "v"(a));
    return d;
}

__device__ __forceinline__ unsigned cvtpk(float lo, float hi) {
    unsigned r;
    asm("v_cvt_pk_bf16_f32 %0, %1, %2" : "=v"(r) : "v"(lo), "v"(hi));
    return r;
}

// v_permlane32_swap_b32: SAFE only with two independently-computed values
// (P-pack, proven R7). BROKEN as copy-then-swap self-reduce (R6/R8).
__device__ __forceinline__ void swap32(unsigned &a, unsigned &b) {
    asm volatile("v_permlane32_swap_b32 %0, %1" : "+v"(a), "+v"(b));
}
__device__ __forceinline__ float xmax32(float x) {
    return fmaxf(x, __shfl_xor(x, 32));
}
__device__ __forceinline__ float xsum32(float x) {
    return x + __shfl_xor(x, 32);
}

__device__ __forceinline__ bf8 pack_bf8(f32x4 a, f32x4 b) {
    bf8 v;
    v[0]=(short)f2bf(a[0]); v[1]=(short)f2bf(a[1]);
    v[2]=(short)f2bf(a[2]); v[3]=(short)f2bf(a[3]);
    v[4]=(short)f2bf(b[0]); v[5]=(short)f2bf(b[1]);
    v[6]=(short)f2bf(b[2]); v[7]=(short)f2bf(b[3]);
    return v;
}

__device__ __forceinline__ bf8 mk_bf8(i32x2 a, i32x2 b) {
    union { i32x2 h[2]; bf8 v; } u;
    u.h[0] = a; u.h[1] = b;
    return u.v;
}
__device__ __forceinline__ bf8 mk_bf8w(unsigned w0, unsigned w1, unsigned w2, unsigned w3) {
    union { unsigned w[4]; bf8 v; } u;
    u.w[0] = w0; u.w[1] = w1; u.w[2] = w2; u.w[3] = w3;
    return u.v;
}

__global__ __launch_bounds__(256, 2)
void attn_fwd(const float* __restrict__ Q,
              const float* __restrict__ TK,
              const float* __restrict__ TV,
              const float* __restrict__ CK,
              const float* __restrict__ CV,
              const float* __restrict__ BP,
              float* __restrict__ OUT)
{
    // 4 waves x 32 q-rows = 128 q-rows/block. Swapped QK^T and PV (q = lane&31):
    //   S^T[kv][q] = mfma(A=K, B=Q^T);  O^T[d][q] = mfma(A=V^T(tr_read), B=P)
    // 2 KV tiles per barrier: 4 LDS buffers (pair parity x half).
    // K: XOR-swizzle folded into global source col; LINEAR ds_write.
    // V: tr_read tile permutation folded into global source addr; LINEAR write.
    __shared__ __align__(16) unsigned short Ks[4][KVB * DH];   // 4 x 8 KB
    __shared__ __align__(16) unsigned short Vs[4][KVB * DH];   // 4 x 8 KB

    const int tid = threadIdx.x;
    const int w   = tid >> 6;
    const int l   = tid & 63;
    const int r31 = l & 31;
    const int hi  = l >> 5;

    // XCD-aware mapping: 512 blocks = 8 XCD x 4 bh x 16 q-tiles
    const int bid = blockIdx.x;
    const int xcd = bid & 7;
    const int sub = bid >> 3;
    const int bh  = xcd * 4 + (sub >> 4);
    const int qt  = sub & 15;
    const int bb  = bh >> 4;
    const int hh  = bh & 15;

    const float biasl = BP[0] * LOG2E;     // log2-domain bias

    // ---- Q fragments (B-operand), pre-scaled by SCALE*log2(e) ----
    const int qrow = qt * 128 + w * 32 + r31;
    const float* qp = Q + (((size_t)bb * ST + qrow) * NH + hh) * DH;
    const float qsc = SCALE * LOG2E;
    bf8 qf[8];
#pragma unroll
    for (int dk = 0; dk < 8; ++dk) {
        const f32x4 x0 = *(const f32x4*)(qp + dk * 16 + hi * 8);
        const f32x4 x1 = *(const f32x4*)(qp + dk * 16 + hi * 8 + 4);
        bf8 v;
        v[0]=(short)f2bf(x0[0]*qsc); v[1]=(short)f2bf(x0[1]*qsc);
        v[2]=(short)f2bf(x0[2]*qsc); v[3]=(short)f2bf(x0[3]*qsc);
        v[4]=(short)f2bf(x1[0]*qsc); v[5]=(short)f2bf(x1[1]*qsc);
        v[6]=(short)f2bf(x1[2]*qsc); v[7]=(short)f2bf(x1[3]*qsc);
        qf[dk] = v;
    }

    f32x16 oa[4];
#pragma unroll
    for (int dt = 0; dt < 4; ++dt)
#pragma unroll
        for (int e = 0; e < 16; ++e) oa[dt][e] = 0.f;
    float m_run = -1e30f, l_run = 0.f;

    // ---- loop-invariant staging offsets (hoisted out of the K-loop) ----
    int koff[2], voff[2];
#pragma unroll
    for (int i = 0; i < 2; ++i) {
        const int c = tid + (i << 8);
        const int krow = c >> 4;
        const int kcol = ((c & 15) ^ (krow & 7)) << 3;
        koff[i] = krow * (NH * DH) + kcol;
        const int vkv = (((c >> 8) & 1) << 4) | (((c >> 4) & 1) << 3)
                      | (((c >> 7) & 1) << 2) | ((c >> 1) & 3);
        const int vd  = (((c >> 5) & 3) << 5) | (((c >> 3) & 1) << 4)
                      | ((c & 1) << 3);
        voff[i] = vkv * (NH * DH) + vd;
    }

    // staging registers: 2 tiles x 2 chunks x 2 halves (issue-early/write-late)
    f32x4 skr[2][2][2], svr[2][2][2];

    auto stage_load = [&](int p) {
#pragma unroll
        for (int ti = 0; ti < 2; ++ti) {
            const int kv0 = (2 * p + ti) * KVB;
            const float *kb, *vb;
            if (kv0 < ST) {
                const size_t off = (((size_t)bb * ST + kv0) * NH + hh) * DH;
                kb = TK + off; vb = TV + off;
            } else {
                const size_t off = (((size_t)bb * SC + (kv0 - ST)) * NH + hh) * DH;
                kb = CK + off; vb = CV + off;
            }
#pragma unroll
            for (int i = 0; i < 2; ++i) {
                const float* kp = kb + koff[i];
                skr[ti][i][0] = *(const f32x4*)kp;
                skr[ti][i][1] = *(const f32x4*)(kp + 4);
                const float* vp = vb + voff[i];
                svr[ti][i][0] = *(const f32x4*)vp;
                svr[ti][i][1] = *(const f32x4*)(vp + 4);
            }
        }
    };

    auto stage_write = [&](int pb) {       // writes buffer set {2pb, 2pb+1}
#pragma unroll
        for (int ti = 0; ti < 2; ++ti) {
            char* kd = (char*)Ks[2 * pb + ti];
            char* vd = (char*)Vs[2 * pb + ti];
#pragma unroll
            for (int i = 0; i < 2; ++i) {
                const int c = tid + (i << 8);
                *(bf8*)(kd + c * 16) = pack_bf8(skr[ti][i][0], skr[ti][i][1]);
                *(bf8*)(vd + c * 16) = pack_bf8(svr[ti][i][0], svr[ti][i][1]);
            }
        }
    };

    stage_load(0);
    stage_write(0);

    const unsigned vLane = (unsigned)(size_t)&Vs[0][0]
                         + (unsigned)((l >> 4) * 128 + (l & 15) * 8);
    const char* kBase = (const char*)Ks[0];

    for (int tp = 0; tp < NP; ++tp) {
        __syncthreads();                       // set (tp&1) visible; other free
        if (tp + 1 < NP) stage_load(tp + 1);   // issue pair loads, write at end
        const float bias = (tp >= TGTP) ? biasl : 0.f;

#pragma unroll
        for (int hf = 0; hf < 2; ++hf) {
            const int buf = ((tp & 1) << 1) | hf;
            const unsigned kOff = (unsigned)buf << 13;

            // ---- QK^T swapped: two interleaved accumulators ----
            f32x16 s0, s1;
#pragma unroll
            for (int e = 0; e < 16; ++e) { s0[e] = 0.f; s1[e] = 0.f; }
            __builtin_amdgcn_s_setprio(1);
#pragma unroll
            for (int dk = 0; dk < 8; dk += 2) {
                int o0 = r31 * 256 + (dk * 16 + hi * 8) * 2;
                o0 ^= (r31 & 7) << 4;
                const bf8 kf0 = *(const bf8*)(kBase + kOff + o0);
                s0 = __builtin_amdgcn_mfma_f32_32x32x16_bf16(kf0, qf[dk], s0, 0, 0, 0);
                int o1 = r31 * 256 + ((dk + 1) * 16 + hi * 8) * 2;
                o1 ^= (r31 & 7) << 4;
                const bf8 kf1 = *(const bf8*)(kBase + kOff + o1);
                s1 = __builtin_amdgcn_mfma_f32_32x32x16_bf16(kf1, qf[dk + 1], s1, 0, 0, 0);
            }
            __builtin_amdgcn_s_setprio(0);

            // ---- V tr-reads; latency hides under softmax ----
            asm volatile("" ::: "memory");
            const unsigned vA = vLane + ((unsigned)buf << 13);
            i32x2 vt_[2][4][2];
#pragma unroll
            for (int ks = 0; ks < 2; ++ks) {
                const unsigned vk = vA + (unsigned)(ks << 12);
#pragma unroll
                for (int dt = 0; dt < 4; ++dt) {
                    vt_[ks][dt][0] = tr_read(vk + dt * 512);
                    vt_[ks][dt][1] = tr_read(vk + dt * 512 + 2048);
                }
            }

            float p[16];
#pragma unroll
            for (int e = 0; e < 16; ++e) p[e] = s0[e] + s1[e];

            // ---- in-register online softmax, log2 domain, defer-max ----
            float mx = p[0];
#pragma unroll
            for (int e = 1; e < 16; ++e) mx = fmaxf(mx, p[e]);
            mx = xmax32(mx) + bias;
            const int need = (mx > m_run + 11.54f) ? 1 : 0;   // = 8 nats
            if (__any(need)) {
                const float mnew = fmaxf(m_run, mx);
                const float corr = __builtin_amdgcn_exp2f(m_run - mnew);
                m_run = mnew;
                l_run *= corr;
#pragma unroll
                for (int dt = 0; dt < 4; ++dt)
#pragma unroll
                    for (int e = 0; e < 16; ++e) oa[dt][e] *= corr;
            }
            const float zb = bias - m_run;
            float rs = 0.f;
#pragma unroll
            for (int e = 0; e < 16; ++e) {
                p[e] = __builtin_amdgcn_exp2f(p[e] + zb);
                rs += p[e];
            }
            l_run += xsum32(rs);

            // ---- pack P -> B-operand fragments (cvt_pk + permlane) ----
            unsigned a0 = cvtpk(p[0], p[1]),  b0 = cvtpk(p[4], p[5]);
            unsigned a1 = cvtpk(p[2], p[3]),  b1 = cvtpk(p[6], p[7]);
            swap32(a0, b0); swap32(a1, b1);
            const bf8 pf0 = mk_bf8w(a0, a1, b0, b1);
            unsigned a2 = cvtpk(p[8], p[9]),   b2 = cvtpk(p[12], p[13]);
            unsigned a3 = cvtpk(p[10], p[11]), b3 = cvtpk(p[14], p[15]);
            swap32(a2, b2); swap32(a3, b3);
            const bf8 pf1 = mk_bf8w(a2, a3, b2, b3);

            // ---- PV swapped: single 8-MFMA cluster ----
            asm volatile("s_waitcnt lgkmcnt(0)");
            __builtin_amdgcn_sched_barrier(0);
            __builtin_amdgcn_s_setprio(1);
#pragma unroll
            for (int ks = 0; ks < 2; ++ks) {
                const bf8 pf = ks ? pf1 : pf0;
#pragma unroll
                for (int dt = 0; dt < 4; ++dt) {
                    const bf8 vf = mk_bf8(vt_[ks][dt][0], vt_[ks][dt][1]);
                    oa[dt] = __builtin_amdgcn_mfma_f32_32x32x16_bf16(vf, pf, oa[dt], 0, 0, 0);
                }
            }
            __builtin_amdgcn_s_setprio(0);
        }

        // ---- write-late: next pair's staged regs -> other buffer set ----
        if (tp + 1 < NP) stage_write((tp + 1) & 1);
    }

    // ---- epilogue: normalize, store fp32; lane owns q=r31 ----
    const float inv = 1.0f / l_run;
    float* op = OUT + ((size_t)(bb * ST + qrow)) * (NH * DH) + hh * DH;
#pragma unroll
    for (int dt = 0; dt < 4; ++dt)
#pragma unroll
        for (int rr = 0; rr < 4; ++rr) {
            f32x4 st;
            st[0] = oa[dt][rr * 4 + 0] * inv;
            st[1] = oa[dt][rr * 4 + 1] * inv;
            st[2] = oa[dt][rr * 4 + 2] * inv;
            st[3] = oa[dt][rr * 4 + 3] * inv;
            *(f32x4*)(op + dt * 32 + rr * 8 + hi * 4) = st;
        }
}

extern "C" void kernel_launch(void* const* d_in, const int* in_sizes, int n_in,
                              void* d_out, int out_size, void* d_ws, size_t ws_size,
                              hipStream_t stream) {
    const float* q  = (const float*)d_in[0];
    const float* tk = (const float*)d_in[1];
    const float* tv = (const float*)d_in[2];
    const float* ck = (const float*)d_in[3];
    const float* cv = (const float*)d_in[4];
    const float* bp = (const float*)d_in[5];
    float* out = (float*)d_out;
    attn_fwd<<<dim3((ST / 128) * B_ * NH), 256, 0, stream>>>(q, tk, tv, ck, cv, bp, out);
}